// Round 1
// baseline (12768.764 us; speedup 1.0000x reference)
//
#include <hip/hip_runtime.h>
#include <hip/hip_bf16.h>
#include <stdint.h>

// SparseMLP: out[nz blocks] = (x[nz blocks] @ W1) @ W2, other blocks zero.
// Memory-bound (~960 MiB min HBM traffic); fp32 SGEMM tiles, H staged bf16 in d_ws.

#define TILE 128
#define BK 16
#define PAD 4
#define LDSROW (TILE + PAD)

__device__ inline unsigned short f2bf(float f) {
    unsigned int u = __float_as_uint(f);
    unsigned int r = (u + 0x7FFFu + ((u >> 16) & 1u)) >> 16;  // RNE
    return (unsigned short)r;
}

// ---------------- zero inactive output blocks ----------------
__global__ __launch_bounds__(256) void zero_kernel(
    float* __restrict__ out, const int* __restrict__ nz, int nnz)
{
    const int OUTD = 4096;
    int b = blockIdx.x;  // 0..63
    bool active = false;
    for (int i = 0; i < nnz; ++i) active |= (nz[i] == b);
    if (active) return;
    float4* p = (float4*)(out + (size_t)b * 128 * OUTD);
    const int total = 128 * OUTD / 4;  // 131072 float4
    const float4 z = make_float4(0.f, 0.f, 0.f, 0.f);
    for (int i = threadIdx.x + blockIdx.y * 256; i < total; i += 256 * gridDim.y)
        p[i] = z;
}

// ---------------- GEMM1: H = gather(x) @ W1, bf16 out ----------------
__global__ __launch_bounds__(256, 4) void gemm1_kernel(
    const float* __restrict__ x, const float* __restrict__ w1,
    const int* __restrict__ nz, unsigned short* __restrict__ h)
{
    const int EMBED = 4096, HIDDEN = 16384;
    __shared__ float As[BK][LDSROW];
    __shared__ float Bs[BK][LDSROW];
    const int by = blockIdx.x;   // M-tile (fast-varying: 32 tiles share W1 stripe)
    const int bx = blockIdx.y;   // N-tile
    const int t = threadIdx.x;
    const int tx = t & 15, ty = t >> 4;
    const int blk = nz[by];
    const float* xsrc = x + (size_t)blk * 128 * EMBED;
    const int n0 = bx * TILE;

    float acc[8][8];
    #pragma unroll
    for (int i = 0; i < 8; ++i)
        #pragma unroll
        for (int j = 0; j < 8; ++j) acc[i][j] = 0.f;

    for (int k0 = 0; k0 < EMBED; k0 += BK) {
        // A tile: 128 rows x 16 k  (512 float4, 2 per thread), store transposed
        #pragma unroll
        for (int i = 0; i < 2; ++i) {
            int idx = t + i * 256;
            int row = idx >> 2;
            int kc = (idx & 3) << 2;
            const float4 v = *(const float4*)(xsrc + (size_t)row * EMBED + k0 + kc);
            As[kc + 0][row] = v.x; As[kc + 1][row] = v.y;
            As[kc + 2][row] = v.z; As[kc + 3][row] = v.w;
        }
        // B tile: 16 k-rows x 128 cols (512 float4, 2 per thread)
        #pragma unroll
        for (int i = 0; i < 2; ++i) {
            int idx = t + i * 256;
            int kr = idx >> 5;
            int nc = (idx & 31) << 2;
            const float4 v = *(const float4*)(w1 + (size_t)(k0 + kr) * HIDDEN + n0 + nc);
            *(float4*)&Bs[kr][nc] = v;
        }
        __syncthreads();
        #pragma unroll
        for (int kk = 0; kk < BK; ++kk) {
            float a[8], b[8];
            *(float4*)&a[0] = *(const float4*)&As[kk][ty * 8];
            *(float4*)&a[4] = *(const float4*)&As[kk][ty * 8 + 4];
            *(float4*)&b[0] = *(const float4*)&Bs[kk][tx * 8];
            *(float4*)&b[4] = *(const float4*)&Bs[kk][tx * 8 + 4];
            #pragma unroll
            for (int i = 0; i < 8; ++i)
                #pragma unroll
                for (int j = 0; j < 8; ++j)
                    acc[i][j] = fmaf(a[i], b[j], acc[i][j]);
        }
        __syncthreads();
    }
    // epilogue: pack 8 bf16 per row-frag, one 16B store
    #pragma unroll
    for (int i = 0; i < 8; ++i) {
        size_t row = (size_t)(by * TILE + ty * 8 + i);
        unsigned short tmp[8];
        #pragma unroll
        for (int j = 0; j < 8; ++j) tmp[j] = f2bf(acc[i][j]);
        *(uint4*)(h + row * HIDDEN + n0 + tx * 8) = *(const uint4*)tmp;
    }
}

// ---------------- GEMM2: out[nz] = H(bf16) @ W2 ----------------
__global__ __launch_bounds__(256, 4) void gemm2_kernel(
    const unsigned short* __restrict__ h, const float* __restrict__ w2,
    const int* __restrict__ nz, float* __restrict__ out)
{
    const int HIDDEN = 16384, OUTD = 4096;
    __shared__ float As[BK][LDSROW];
    __shared__ float Bs[BK][LDSROW];
    const int by = blockIdx.x;   // M-tile
    const int bx = blockIdx.y;   // N-tile
    const int t = threadIdx.x;
    const int tx = t & 15, ty = t >> 4;
    const unsigned short* hsrc = h + (size_t)by * TILE * HIDDEN;
    const int n0 = bx * TILE;

    float acc[8][8];
    #pragma unroll
    for (int i = 0; i < 8; ++i)
        #pragma unroll
        for (int j = 0; j < 8; ++j) acc[i][j] = 0.f;

    for (int k0 = 0; k0 < HIDDEN; k0 += BK) {
        // A tile: 128 rows x 16 k bf16 (one 16B = 8 bf16 per thread)
        {
            int row = t >> 1;
            int kc = (t & 1) << 3;
            uint4 v = *(const uint4*)(hsrc + (size_t)row * HIDDEN + k0 + kc);
            unsigned int w[4] = {v.x, v.y, v.z, v.w};
            #pragma unroll
            for (int q = 0; q < 4; ++q) {
                As[kc + 2 * q + 0][row] = __uint_as_float(w[q] << 16);
                As[kc + 2 * q + 1][row] = __uint_as_float(w[q] & 0xFFFF0000u);
            }
        }
        // B tile: 16 k-rows x 128 cols
        #pragma unroll
        for (int i = 0; i < 2; ++i) {
            int idx = t + i * 256;
            int kr = idx >> 5;
            int nc = (idx & 31) << 2;
            const float4 v = *(const float4*)(w2 + (size_t)(k0 + kr) * OUTD + n0 + nc);
            *(float4*)&Bs[kr][nc] = v;
        }
        __syncthreads();
        #pragma unroll
        for (int kk = 0; kk < BK; ++kk) {
            float a[8], b[8];
            *(float4*)&a[0] = *(const float4*)&As[kk][ty * 8];
            *(float4*)&a[4] = *(const float4*)&As[kk][ty * 8 + 4];
            *(float4*)&b[0] = *(const float4*)&Bs[kk][tx * 8];
            *(float4*)&b[4] = *(const float4*)&Bs[kk][tx * 8 + 4];
            #pragma unroll
            for (int i = 0; i < 8; ++i)
                #pragma unroll
                for (int j = 0; j < 8; ++j)
                    acc[i][j] = fmaf(a[i], b[j], acc[i][j]);
        }
        __syncthreads();
    }
    // epilogue: scatter to output block nz[by]
    const int blk = nz[by];
    #pragma unroll
    for (int i = 0; i < 8; ++i) {
        size_t orow = (size_t)blk * TILE + ty * 8 + i;
        float* dst = out + orow * OUTD + n0 + tx * 8;
        *(float4*)dst = make_float4(acc[i][0], acc[i][1], acc[i][2], acc[i][3]);
        *(float4*)(dst + 4) = make_float4(acc[i][4], acc[i][5], acc[i][6], acc[i][7]);
    }
}

extern "C" void kernel_launch(void* const* d_in, const int* in_sizes, int n_in,
                              void* d_out, int out_size, void* d_ws, size_t ws_size,
                              hipStream_t stream) {
    const float* x  = (const float*)d_in[0];
    const float* w1 = (const float*)d_in[1];
    const float* w2 = (const float*)d_in[2];
    const int* nz   = (const int*)d_in[3];
    const int nnz   = in_sizes[3];              // 32
    float* out = (float*)d_out;
    unsigned short* h = (unsigned short*)d_ws;  // bf16 H: 4096 x 16384 (128 MiB)

    const int rows = in_sizes[0] / 4096;        // 8192
    const int nblocks = rows / 128;             // 64

    zero_kernel<<<dim3(nblocks, 32), 256, 0, stream>>>(out, nz, nnz);
    gemm1_kernel<<<dim3(nnz, 16384 / TILE), 256, 0, stream>>>(x, w1, nz, h);
    gemm2_kernel<<<dim3(nnz, 4096 / TILE), 256, 0, stream>>>(h, w2, nz, out);
}

// Round 2
// 2154.826 us; speedup vs baseline: 5.9257x; 5.9257x over previous
//
#include <hip/hip_runtime.h>
#include <hip/hip_bf16.h>
#include <stdint.h>

// SparseMLP on MI355X. Compute-bound at fp32 (1.1 TFLOP / 157 TF = 7 ms floor),
// so: convert inputs/weights to fp16 (memory-bound pre-passes, ~140 us), then
// two MFMA f16 GEMMs (m97 structure: 128x128 tile, BK=32, global_load_lds x16,
// 2-barrier K-loop). Fallback to fp32-VALU path if ws_size < 416 MiB.

typedef __attribute__((ext_vector_type(8))) _Float16 half8;
typedef __attribute__((ext_vector_type(4))) float f32x4;

__device__ __forceinline__ void gld_lds16(const void* g, void* l) {
    __builtin_amdgcn_global_load_lds(
        (const __attribute__((address_space(1))) unsigned int*)g,
        (__attribute__((address_space(3))) unsigned int*)l, 16, 0, 0);
}

// ---------------- zero inactive output blocks ----------------
__global__ __launch_bounds__(256) void zero_kernel(
    float* __restrict__ out, const int* __restrict__ nz, int nnz)
{
    const int OUTD = 4096;
    int b = blockIdx.x;  // 0..63
    bool active = false;
    for (int i = 0; i < nnz; ++i) active |= (nz[i] == b);
    if (active) return;
    float4* p = (float4*)(out + (size_t)b * 128 * OUTD);
    const int total = 128 * OUTD / 4;
    const float4 z = make_float4(0.f, 0.f, 0.f, 0.f);
    for (int i = threadIdx.x + blockIdx.y * 256; i < total; i += 256 * gridDim.y)
        p[i] = z;
}

// ---------------- convert+transpose W (KxN fp32) -> (NxK fp16) ----------------
__global__ __launch_bounds__(256) void convT_kernel(
    const float* __restrict__ src, _Float16* __restrict__ dst, int K, int N)
{
    __shared__ float t[64][65];
    const int nb = blockIdx.x * 64, kb = blockIdx.y * 64;
    const int tid = threadIdx.x;
    #pragma unroll
    for (int i = 0; i < 4; ++i) {
        int idx = tid + i * 256;
        int r = idx >> 4, c4 = (idx & 15) * 4;
        float4 v = *(const float4*)(src + (size_t)(kb + r) * N + nb + c4);
        t[r][c4 + 0] = v.x; t[r][c4 + 1] = v.y;
        t[r][c4 + 2] = v.z; t[r][c4 + 3] = v.w;
    }
    __syncthreads();
    #pragma unroll
    for (int i = 0; i < 2; ++i) {
        int idx = tid + i * 256;
        int rn = idx >> 3, c8 = (idx & 7) * 8;
        _Float16 tmp[8];
        #pragma unroll
        for (int j = 0; j < 8; ++j) tmp[j] = (_Float16)t[c8 + j][rn];
        *(uint4*)(dst + (size_t)(nb + rn) * K + kb + c8) = *(const uint4*)tmp;
    }
}

// ---------------- gather+convert x -> xg fp16 (4096 x 4096) ----------------
__global__ __launch_bounds__(256) void convx_kernel(
    const float* __restrict__ x, const int* __restrict__ nz, _Float16* __restrict__ xg)
{
    const int EMBED = 4096;
    int row = blockIdx.x;  // active row 0..4095
    int blk = nz[row >> 7];
    const float* src = x + ((size_t)blk * 128 + (row & 127)) * EMBED;
    _Float16* dst = xg + (size_t)row * EMBED;
    for (int i = threadIdx.x; i < EMBED / 4; i += 256) {
        float4 v = *(const float4*)(src + i * 4);
        _Float16 tmp[4] = {(_Float16)v.x, (_Float16)v.y, (_Float16)v.z, (_Float16)v.w};
        *(uint2*)(dst + i * 4) = *(const uint2*)tmp;
    }
}

// ---------------- MFMA f16 GEMM: H = xg @ W1  (A MxK, BT NxK, out fp16 MxN) --
__global__ __launch_bounds__(256) void gemm1_f16_kernel(
    const _Float16* __restrict__ A,   // 4096 x 4096
    const _Float16* __restrict__ BT,  // 16384 x 4096
    _Float16* __restrict__ H)         // 4096 x 16384
{
    const int K = 4096, N = 16384;
    __shared__ __align__(16) _Float16 Asm[128 * 32];
    __shared__ __align__(16) _Float16 Bsm[128 * 32];
    const int tid = threadIdx.x;
    const int lane = tid & 63, wid = tid >> 6;
    const int m0 = blockIdx.x * 128, n0 = blockIdx.y * 128;

    const int c0 = tid, c1 = tid + 256;
    const _Float16* gA0 = A + (size_t)(m0 + (c0 >> 2)) * K + (c0 & 3) * 8;
    const _Float16* gA1 = A + (size_t)(m0 + (c1 >> 2)) * K + (c1 & 3) * 8;
    const _Float16* gB0 = BT + (size_t)(n0 + (c0 >> 2)) * K + (c0 & 3) * 8;
    const _Float16* gB1 = BT + (size_t)(n0 + (c1 >> 2)) * K + (c1 & 3) * 8;
    char* lA0 = (char*)Asm + c0 * 16; char* lA1 = (char*)Asm + c1 * 16;
    char* lB0 = (char*)Bsm + c0 * 16; char* lB1 = (char*)Bsm + c1 * 16;

    const int wm = (wid & 1) * 64, wn = (wid >> 1) * 64;
    const int fr = lane & 15, fq = lane >> 4;

    f32x4 acc[4][4];
    #pragma unroll
    for (int i = 0; i < 4; ++i)
        #pragma unroll
        for (int j = 0; j < 4; ++j) acc[i][j] = (f32x4)(0.f);

    for (int k0 = 0; k0 < K; k0 += 32) {
        gld_lds16(gA0 + k0, lA0); gld_lds16(gA1 + k0, lA1);
        gld_lds16(gB0 + k0, lB0); gld_lds16(gB1 + k0, lB1);
        __syncthreads();
        half8 af[4], bf[4];
        #pragma unroll
        for (int i = 0; i < 4; ++i)
            af[i] = *(const half8*)&Asm[(wm + i * 16 + fr) * 32 + fq * 8];
        #pragma unroll
        for (int j = 0; j < 4; ++j)
            bf[j] = *(const half8*)&Bsm[(wn + j * 16 + fr) * 32 + fq * 8];
        #pragma unroll
        for (int i = 0; i < 4; ++i)
            #pragma unroll
            for (int j = 0; j < 4; ++j)
                acc[i][j] = __builtin_amdgcn_mfma_f32_16x16x32_f16(af[i], bf[j], acc[i][j], 0, 0, 0);
        __syncthreads();
    }
    #pragma unroll
    for (int i = 0; i < 4; ++i)
        #pragma unroll
        for (int j = 0; j < 4; ++j)
            #pragma unroll
            for (int r = 0; r < 4; ++r) {
                int m = m0 + wm + i * 16 + fq * 4 + r;
                int n = n0 + wn + j * 16 + fr;
                H[(size_t)m * N + n] = (_Float16)acc[i][j][r];
            }
}

// ---------------- MFMA f16 GEMM2: out[nz] = H @ W2 ----------------
__global__ __launch_bounds__(256) void gemm2_f16_kernel(
    const _Float16* __restrict__ A,   // H: 4096 x 16384
    const _Float16* __restrict__ BT,  // W2T: 4096 x 16384
    const int* __restrict__ nz, float* __restrict__ out)
{
    const int K = 16384, N = 4096;
    __shared__ __align__(16) _Float16 Asm[128 * 32];
    __shared__ __align__(16) _Float16 Bsm[128 * 32];
    const int tid = threadIdx.x;
    const int lane = tid & 63, wid = tid >> 6;
    const int m0 = blockIdx.x * 128, n0 = blockIdx.y * 128;

    const int c0 = tid, c1 = tid + 256;
    const _Float16* gA0 = A + (size_t)(m0 + (c0 >> 2)) * K + (c0 & 3) * 8;
    const _Float16* gA1 = A + (size_t)(m0 + (c1 >> 2)) * K + (c1 & 3) * 8;
    const _Float16* gB0 = BT + (size_t)(n0 + (c0 >> 2)) * K + (c0 & 3) * 8;
    const _Float16* gB1 = BT + (size_t)(n0 + (c1 >> 2)) * K + (c1 & 3) * 8;
    char* lA0 = (char*)Asm + c0 * 16; char* lA1 = (char*)Asm + c1 * 16;
    char* lB0 = (char*)Bsm + c0 * 16; char* lB1 = (char*)Bsm + c1 * 16;

    const int wm = (wid & 1) * 64, wn = (wid >> 1) * 64;
    const int fr = lane & 15, fq = lane >> 4;

    f32x4 acc[4][4];
    #pragma unroll
    for (int i = 0; i < 4; ++i)
        #pragma unroll
        for (int j = 0; j < 4; ++j) acc[i][j] = (f32x4)(0.f);

    for (int k0 = 0; k0 < K; k0 += 32) {
        gld_lds16(gA0 + k0, lA0); gld_lds16(gA1 + k0, lA1);
        gld_lds16(gB0 + k0, lB0); gld_lds16(gB1 + k0, lB1);
        __syncthreads();
        half8 af[4], bf[4];
        #pragma unroll
        for (int i = 0; i < 4; ++i)
            af[i] = *(const half8*)&Asm[(wm + i * 16 + fr) * 32 + fq * 8];
        #pragma unroll
        for (int j = 0; j < 4; ++j)
            bf[j] = *(const half8*)&Bsm[(wn + j * 16 + fr) * 32 + fq * 8];
        #pragma unroll
        for (int i = 0; i < 4; ++i)
            #pragma unroll
            for (int j = 0; j < 4; ++j)
                acc[i][j] = __builtin_amdgcn_mfma_f32_16x16x32_f16(af[i], bf[j], acc[i][j], 0, 0, 0);
        __syncthreads();
    }
    const int nzb = nz[blockIdx.x];
    #pragma unroll
    for (int i = 0; i < 4; ++i)
        #pragma unroll
        for (int j = 0; j < 4; ++j)
            #pragma unroll
            for (int r = 0; r < 4; ++r) {
                int mloc = wm + i * 16 + fq * 4 + r;      // 0..127 within tile
                int n = n0 + wn + j * 16 + fr;
                out[((size_t)nzb * 128 + mloc) * N + n] = acc[i][j][r];
            }
}

// ================= fallback fp32 path (R1, passed) =================
#define TILE 128
#define BK16 16
#define LDSROW (TILE + 4)

__device__ inline unsigned short f2bf(float f) {
    unsigned int u = __float_as_uint(f);
    return (unsigned short)((u + 0x7FFFu + ((u >> 16) & 1u)) >> 16);
}

__global__ __launch_bounds__(256, 4) void gemm1_fp32_kernel(
    const float* __restrict__ x, const float* __restrict__ w1,
    const int* __restrict__ nz, unsigned short* __restrict__ h)
{
    const int EMBED = 4096, HIDDEN = 16384;
    __shared__ float As[BK16][LDSROW];
    __shared__ float Bs[BK16][LDSROW];
    const int by = blockIdx.x, bx = blockIdx.y;
    const int t = threadIdx.x, tx = t & 15, ty = t >> 4;
    const int blk = nz[by];
    const float* xsrc = x + (size_t)blk * 128 * EMBED;
    const int n0 = bx * TILE;
    float acc[8][8];
    #pragma unroll
    for (int i = 0; i < 8; ++i)
        #pragma unroll
        for (int j = 0; j < 8; ++j) acc[i][j] = 0.f;
    for (int k0 = 0; k0 < EMBED; k0 += BK16) {
        #pragma unroll
        for (int i = 0; i < 2; ++i) {
            int idx = t + i * 256, row = idx >> 2, kc = (idx & 3) << 2;
            const float4 v = *(const float4*)(xsrc + (size_t)row * EMBED + k0 + kc);
            As[kc][row] = v.x; As[kc + 1][row] = v.y; As[kc + 2][row] = v.z; As[kc + 3][row] = v.w;
        }
        #pragma unroll
        for (int i = 0; i < 2; ++i) {
            int idx = t + i * 256, kr = idx >> 5, nc = (idx & 31) << 2;
            *(float4*)&Bs[kr][nc] = *(const float4*)(w1 + (size_t)(k0 + kr) * HIDDEN + n0 + nc);
        }
        __syncthreads();
        #pragma unroll
        for (int kk = 0; kk < BK16; ++kk) {
            float a[8], b[8];
            *(float4*)&a[0] = *(const float4*)&As[kk][ty * 8];
            *(float4*)&a[4] = *(const float4*)&As[kk][ty * 8 + 4];
            *(float4*)&b[0] = *(const float4*)&Bs[kk][tx * 8];
            *(float4*)&b[4] = *(const float4*)&Bs[kk][tx * 8 + 4];
            #pragma unroll
            for (int i = 0; i < 8; ++i)
                #pragma unroll
                for (int j = 0; j < 8; ++j) acc[i][j] = fmaf(a[i], b[j], acc[i][j]);
        }
        __syncthreads();
    }
    #pragma unroll
    for (int i = 0; i < 8; ++i) {
        size_t row = (size_t)(by * TILE + ty * 8 + i);
        unsigned short tmp[8];
        #pragma unroll
        for (int j = 0; j < 8; ++j) tmp[j] = f2bf(acc[i][j]);
        *(uint4*)(h + row * HIDDEN + n0 + tx * 8) = *(const uint4*)tmp;
    }
}

__global__ __launch_bounds__(256, 4) void gemm2_fp32_kernel(
    const unsigned short* __restrict__ h, const float* __restrict__ w2,
    const int* __restrict__ nz, float* __restrict__ out)
{
    const int HIDDEN = 16384, OUTD = 4096;
    __shared__ float As[BK16][LDSROW];
    __shared__ float Bs[BK16][LDSROW];
    const int by = blockIdx.x, bx = blockIdx.y;
    const int t = threadIdx.x, tx = t & 15, ty = t >> 4;
    const unsigned short* hsrc = h + (size_t)by * TILE * HIDDEN;
    const int n0 = bx * TILE;
    float acc[8][8];
    #pragma unroll
    for (int i = 0; i < 8; ++i)
        #pragma unroll
        for (int j = 0; j < 8; ++j) acc[i][j] = 0.f;
    for (int k0 = 0; k0 < HIDDEN; k0 += BK16) {
        {
            int row = t >> 1, kc = (t & 1) << 3;
            uint4 v = *(const uint4*)(hsrc + (size_t)row * HIDDEN + k0 + kc);
            unsigned int w[4] = {v.x, v.y, v.z, v.w};
            #pragma unroll
            for (int q = 0; q < 4; ++q) {
                As[kc + 2 * q][row] = __uint_as_float(w[q] << 16);
                As[kc + 2 * q + 1][row] = __uint_as_float(w[q] & 0xFFFF0000u);
            }
        }
        #pragma unroll
        for (int i = 0; i < 2; ++i) {
            int idx = t + i * 256, kr = idx >> 5, nc = (idx & 31) << 2;
            *(float4*)&Bs[kr][nc] = *(const float4*)(w2 + (size_t)(k0 + kr) * OUTD + n0 + nc);
        }
        __syncthreads();
        #pragma unroll
        for (int kk = 0; kk < BK16; ++kk) {
            float a[8], b[8];
            *(float4*)&a[0] = *(const float4*)&As[kk][ty * 8];
            *(float4*)&a[4] = *(const float4*)&As[kk][ty * 8 + 4];
            *(float4*)&b[0] = *(const float4*)&Bs[kk][tx * 8];
            *(float4*)&b[4] = *(const float4*)&Bs[kk][tx * 8 + 4];
            #pragma unroll
            for (int i = 0; i < 8; ++i)
                #pragma unroll
                for (int j = 0; j < 8; ++j) acc[i][j] = fmaf(a[i], b[j], acc[i][j]);
        }
        __syncthreads();
    }
    const int blk = nz[by];
    #pragma unroll
    for (int i = 0; i < 8; ++i) {
        size_t orow = (size_t)blk * TILE + ty * 8 + i;
        float* dst = out + orow * OUTD + n0 + tx * 8;
        *(float4*)dst = make_float4(acc[i][0], acc[i][1], acc[i][2], acc[i][3]);
        *(float4*)(dst + 4) = make_float4(acc[i][4], acc[i][5], acc[i][6], acc[i][7]);
    }
}

extern "C" void kernel_launch(void* const* d_in, const int* in_sizes, int n_in,
                              void* d_out, int out_size, void* d_ws, size_t ws_size,
                              hipStream_t stream) {
    const float* x  = (const float*)d_in[0];
    const float* w1 = (const float*)d_in[1];
    const float* w2 = (const float*)d_in[2];
    const int* nz   = (const int*)d_in[3];
    const int nnz   = in_sizes[3];  // 32
    float* out = (float*)d_out;

    const int EMBED = 4096, HIDDEN = 16384, OUTD = 4096;
    const int rows = in_sizes[0] / EMBED;   // 8192
    const int nblocks = rows / 128;         // 64
    const int arows = nnz * 128;            // 4096 active rows

    const size_t MiB = 1024 * 1024;
    const size_t offXG = 0;                 // 32 MiB fp16
    const size_t offW1T = 32 * MiB;         // 128 MiB fp16 (16384 x 4096)
    const size_t offW2T = 160 * MiB;        // 128 MiB fp16 (4096 x 16384)
    const size_t offH = 288 * MiB;          // 128 MiB fp16 (4096 x 16384)
    const size_t need = 416 * MiB;

    zero_kernel<<<dim3(nblocks, 32), 256, 0, stream>>>(out, nz, nnz);

    if (ws_size >= need) {
        _Float16* xg  = (_Float16*)((char*)d_ws + offXG);
        _Float16* w1t = (_Float16*)((char*)d_ws + offW1T);
        _Float16* w2t = (_Float16*)((char*)d_ws + offW2T);
        _Float16* h   = (_Float16*)((char*)d_ws + offH);
        convT_kernel<<<dim3(HIDDEN / 64, EMBED / 64), 256, 0, stream>>>(w1, w1t, EMBED, HIDDEN);
        convT_kernel<<<dim3(OUTD / 64, HIDDEN / 64), 256, 0, stream>>>(w2, w2t, HIDDEN, OUTD);
        convx_kernel<<<dim3(arows), 256, 0, stream>>>(x, nz, xg);
        gemm1_f16_kernel<<<dim3(arows / 128, HIDDEN / 128), 256, 0, stream>>>(xg, w1t, h);
        gemm2_f16_kernel<<<dim3(arows / 128, OUTD / 128), 256, 0, stream>>>(h, w2t, nz, out);
    } else {
        unsigned short* h = (unsigned short*)d_ws;  // bf16 H (128 MiB)
        gemm1_fp32_kernel<<<dim3(nnz, HIDDEN / TILE), 256, 0, stream>>>(x, w1, nz, h);
        gemm2_fp32_kernel<<<dim3(nnz, OUTD / TILE), 256, 0, stream>>>(h, w2, nz, out);
    }
}